// Round 3
// baseline (130.967 us; speedup 1.0000x reference)
//
#include <hip/hip_runtime.h>
#include <hip/hip_bf16.h>

// ODEFunc CNF dynamics, B=1e6 rows, H=64:
//   h1 = elu(W1 z + b1); h2 = W2 h1 + b2; out01 = W3 elu(h2)+b3;
//   trace = sum_k elu'(h2_k) * (G ex1)_k with G[k,j]=W2[k,j]*(c_k w0_j + d_k w1_j)
//
// R6: MFMA rewrite: 74us. R7: consts->LDS, 3 waves/SIMD: 74us (occupancy not
//     the lever -> VALU-inst-throughput bound). R8: trace fold (8 MFMAs fewer,
//     one B-frag set fewer) + v_cvt_pk_bf16_f32: 62.5us, VALUBusy 67%,
//     ~1640 VALU cyc/tile vs ~80 MFMA cyc. Still VALU-bound.
// R9 (this): halve VALU issue via packed-fp32 VOP3P.
//   (a) all elementwise math as float2 -> v_pk_fma_f32/v_pk_mul_f32/
//       v_pk_add_f32 (gfx90a+ packed f32, full rate; min/max/exp stay scalar).
//   (b) b2 folded into MFMA C-init (D[m][n] layout broadcasts b2[m] across n).
//   (c) exp via explicit log2e pre-scale (packed) + __builtin_amdgcn_exp2f
//       (bare v_exp_f32, compiler-managed trans hazard).
//   (d) 4 waves/SIMD (waves_per_eu(4,4), VGPR cap 128, currently 80) + grid
//       2048 to fill the freed issue slots.
// Layouts (m120-verified): A[m=col][k=jt*32+quad*8+jj], B[k][n=col],
//   D[m=mt*16+quad*4+i][n=col].

typedef short bf16x8 __attribute__((ext_vector_type(8)));
typedef float f32x4  __attribute__((ext_vector_type(4)));
typedef float f32x2  __attribute__((ext_vector_type(2)));
typedef int   i32x4  __attribute__((ext_vector_type(4)));

#define LO2(v) __builtin_shufflevector(v, v, 0, 1)
#define HI2(v) __builtin_shufflevector(v, v, 2, 3)

static __device__ __forceinline__ short f2bf(float x) {
    __hip_bfloat16 b = __float2bfloat16(x);
    return __builtin_bit_cast(short, b);
}

// one dword = bf16(lo) | bf16(hi)<<16, single HW instruction
static __device__ __forceinline__ int cvt_pk_bf16(float lo, float hi) {
    int r;
    asm("v_cvt_pk_bf16_f32 %0, %1, %2" : "=v"(r) : "v"(lo), "v"(hi));
    return r;
}

__global__ __launch_bounds__(256) __attribute__((amdgpu_waves_per_eu(4, 4)))
void odefunc_mfma(const float* __restrict__ zin,
                  const float* __restrict__ W1, const float* __restrict__ b1,
                  const float* __restrict__ W2, const float* __restrict__ b2,
                  const float* __restrict__ W3, const float* __restrict__ b3,
                  float* __restrict__ out, int B, int ntiles)
{
    // LDS constant bank, f32x4 units: [0..15]=W1 col0, [16..31]=W1 col1,
    // [32..47]=b1, [48..63]=b2, [64..79]=W3 row0, [80..95]=W3 row1
    __shared__ f32x4 sC[96];

    const int lane = threadIdx.x & 63;
    const int quad = lane >> 4;      // 0..3
    const int col  = lane & 15;      // row-within-tile

    if (threadIdx.x < 64) {
        int i = threadIdx.x;
        float* s = (float*)sC;
        s[i]       = W1[2*i];
        s[64 + i]  = W1[2*i + 1];
        s[128 + i] = b1[i];
        s[192 + i] = b2[i];
        s[256 + i] = W3[i];         // W3[0,:]
        s[320 + i] = W3[64 + i];    // W3[1,:]
    }

    const int wid    = blockIdx.x * (blockDim.x >> 6) + (threadIdx.x >> 6);
    const int nwaves = gridDim.x * (blockDim.x >> 6);

    // ---- Loop-invariant A-operand fragments: W2 and G (trace-folded W2) ----
    // G[k,j] = W2[k,j] * (W3[0,k]*W1[j,0] + W3[1,k]*W1[j,1])
    bf16x8 aW2[4][2], aG[4][2];
#pragma unroll
    for (int mt = 0; mt < 4; ++mt) {
        const int k = mt * 16 + col;
        const float ck = W3[k], dk = W3[64 + k];
#pragma unroll
        for (int jt = 0; jt < 2; ++jt) {
            const float* p = W2 + k * 64 + jt * 32 + quad * 8;
#pragma unroll
            for (int jj = 0; jj < 8; ++jj) {
                int j = jt * 32 + quad * 8 + jj;
                float w2 = p[jj];
                aW2[mt][jt][jj] = f2bf(w2);
                aG[mt][jt][jj]  = f2bf(w2 * fmaf(ck, W1[2*j], dk * W1[2*j+1]));
            }
        }
    }

    const float b30 = b3[0], b31 = b3[1];
    const f32x4 zero4 = {0.f, 0.f, 0.f, 0.f};
    const f32x2 zerop = {0.f, 0.f};
    const f32x2 m1p   = {-1.f, -1.f};
    const f32x2 l2e   = {1.442695040888963f, 1.442695040888963f};

    __syncthreads();

    // ---- coalesced z: lanes 0-47 cover the tile's 16 rows x 3 floats ----
    const int lload = lane < 48 ? lane : 47;
    int t = wid;
    float zv = 0.f;
    if (t < ntiles) zv = zin[t * 48 + lload];

    int cofs = 0;   // opaque zero: defeats LICM on the sC re-reads
    for (; t < ntiles; t += nwaves) {
        asm volatile("" : "+v"(cofs));

        // prefetch next tile's z (hides HBM latency under this tile's compute)
        int tn = t + nwaves;
        int tc = tn < ntiles ? tn : t;
        float zvn = zin[tc * 48 + lload];

        float z0 = __shfl(zv, 3 * col);
        float z1 = __shfl(zv, 3 * col + 1);
        const f32x2 z0p = {z0, z0}, z1p = {z1, z1};

        // ---- layer 1 (branch-free elu, packed f32) -> B-fragments [h | ex1] ----
        bf16x8 Bh[2], Bex[2];
#pragma unroll
        for (int jt = 0; jt < 2; ++jt) {
            int j4 = cofs + jt * 8 + quad * 2;      // f32x4 idx of j0 = jt*32+quad*8
            f32x4 w0a = sC[j4],      w0b = sC[j4 + 1];
            f32x4 w1a = sC[j4 + 16], w1b = sC[j4 + 17];
            f32x4 bba = sC[j4 + 32], bbb = sC[j4 + 33];
            i32x4 ph, pe;
#pragma unroll
            for (int p = 0; p < 4; ++p) {
                f32x2 w0p = (p == 0) ? LO2(w0a) : (p == 1) ? HI2(w0a)
                           : (p == 2) ? LO2(w0b) : HI2(w0b);
                f32x2 w1p = (p == 0) ? LO2(w1a) : (p == 1) ? HI2(w1a)
                           : (p == 2) ? LO2(w1b) : HI2(w1b);
                f32x2 bbp = (p == 0) ? LO2(bba) : (p == 1) ? HI2(bba)
                           : (p == 2) ? LO2(bbb) : HI2(bbb);
                f32x2 a  = __builtin_elementwise_fma(w0p, z0p,
                           __builtin_elementwise_fma(w1p, z1p, bbp));   // 2x pk_fma
                f32x2 am = __builtin_elementwise_min(a, zerop);         // 2x v_min
                f32x2 tt = am * l2e;                                    // pk_mul
                f32x2 e  = { __builtin_amdgcn_exp2f(tt[0]),
                             __builtin_amdgcn_exp2f(tt[1]) };           // 2x v_exp
                f32x2 rl = __builtin_elementwise_max(a, zerop);         // 2x v_max
                f32x2 h  = rl + (e + m1p);                              // 2x pk_add
                ph[p] = cvt_pk_bf16(h[0], h[1]);
                pe[p] = cvt_pk_bf16(e[0], e[1]);
            }
            Bh[jt]  = __builtin_bit_cast(bf16x8, ph);
            Bex[jt] = __builtin_bit_cast(bf16x8, pe);
        }

        // ---- MFMA: accH = W2*h^T + b2 (C-init), accT = G*ex1^T ----
        f32x4 accH[4], accT[4];
        f32x4 w30q[4], w31q[4];
#pragma unroll
        for (int mt = 0; mt < 4; ++mt) {
            int k4 = cofs + 48 + mt * 4 + quad;     // f32x4 idx of k0 = mt*16+quad*4
            f32x4 b2v = sC[k4];
            w30q[mt] = sC[k4 + 16];
            w31q[mt] = sC[k4 + 32];
            accH[mt] = __builtin_amdgcn_mfma_f32_16x16x32_bf16(aW2[mt][0], Bh[0], b2v, 0, 0, 0);
            accH[mt] = __builtin_amdgcn_mfma_f32_16x16x32_bf16(aW2[mt][1], Bh[1], accH[mt], 0, 0, 0);
            accT[mt] = __builtin_amdgcn_mfma_f32_16x16x32_bf16(aG[mt][0], Bex[0], zero4, 0, 0, 0);
            accT[mt] = __builtin_amdgcn_mfma_f32_16x16x32_bf16(aG[mt][1], Bex[1], accT[mt], 0, 0, 0);
        }

        // ---- epilogue (packed f32): elu + W3 fold; trace = ex2 . accT ----
        f32x2 o0p = zerop, o1p = zerop, trcp = zerop;
#pragma unroll
        for (int mt = 0; mt < 4; ++mt) {
#pragma unroll
            for (int half = 0; half < 2; ++half) {
                f32x2 a2  = half ? HI2(accH[mt]) : LO2(accH[mt]);       // b2 already in
                f32x2 at  = half ? HI2(accT[mt]) : LO2(accT[mt]);
                f32x2 w30 = half ? HI2(w30q[mt]) : LO2(w30q[mt]);
                f32x2 w31 = half ? HI2(w31q[mt]) : LO2(w31q[mt]);
                f32x2 am = __builtin_elementwise_min(a2, zerop);
                f32x2 tt = am * l2e;                                    // pk_mul
                f32x2 e  = { __builtin_amdgcn_exp2f(tt[0]),
                             __builtin_amdgcn_exp2f(tt[1]) };
                f32x2 rl = __builtin_elementwise_max(a2, zerop);
                f32x2 hh = rl + (e + m1p);                              // 2x pk_add
                o0p  = __builtin_elementwise_fma(w30, hh, o0p);         // pk_fma
                o1p  = __builtin_elementwise_fma(w31, hh, o1p);         // pk_fma
                trcp = __builtin_elementwise_fma(e, at, trcp);          // pk_fma
            }
        }
        float o0 = o0p[0] + o0p[1];
        float o1 = o1p[0] + o1p[1];
        float trc = trcp[0] + trcp[1];

        // ---- cross-quad reduction (k spans quads): 2 butterfly stages ----
        o0  += __shfl_xor(o0, 16);  o0  += __shfl_xor(o0, 32);
        o1  += __shfl_xor(o1, 16);  o1  += __shfl_xor(o1, 32);
        trc += __shfl_xor(trc, 16); trc += __shfl_xor(trc, 32);

        int row = t * 16 + col;
        if (lane < 16 && row < B) {
            out[3 * row + 0] = o0 + b30;
            out[3 * row + 1] = o1 + b31;
            out[3 * row + 2] = -trc;
        }

        zv = zvn;
    }
}

extern "C" void kernel_launch(void* const* d_in, const int* in_sizes, int n_in,
                              void* d_out, int out_size, void* d_ws, size_t ws_size,
                              hipStream_t stream) {
    // d_in: 0=t(unused) 1=z_and_logp 2=W1 3=b1 4=W2 5=b2 6=W3 7=b3
    const float* zin = (const float*)d_in[1];
    const float* W1  = (const float*)d_in[2];
    const float* b1  = (const float*)d_in[3];
    const float* W2  = (const float*)d_in[4];
    const float* b2  = (const float*)d_in[5];
    const float* W3  = (const float*)d_in[6];
    const float* b3  = (const float*)d_in[7];
    float* out = (float*)d_out;

    int B = in_sizes[1] / 3;
    int ntiles = (B + 15) / 16;
    int grid = 2048;   // 4 waves/SIMD -> 1024 resident blocks -> 2 rounds
    odefunc_mfma<<<grid, 256, 0, stream>>>(zin, W1, b1, W2, b2, W3, b3,
                                           out, B, ntiles);
}

// Round 4
// 123.441 us; speedup vs baseline: 1.0610x; 1.0610x over previous
//
#include <hip/hip_runtime.h>
#include <hip/hip_bf16.h>

// ODEFunc CNF dynamics, B=1e6 rows, H=64:
//   h1 = elu(W1 z + b1); h2 = W2 h1 + b2; out01 = W3 elu(h2)+b3;
//   trace = sum_k elu'(h2_k) * (G ex1)_k with G[k,j]=W2[k,j]*(c_k w0_j + d_k w1_j)
//
// R6: MFMA rewrite: 74us. R7: consts->LDS, 3 waves/SIMD: 74us (VALU-bound,
//     occupancy not the lever). R8: trace fold + v_cvt_pk_bf16_f32: 62.5us.
// R9: packed-f32 VOP3P + b2 C-init fold + waves_per_eu(4,4): 64.6us REGRESSION.
//     WRITE_SIZE 11.7->48.4MB, FETCH 6->16MB: reg cap 128 -> scratch spills
//     (~2.3 dwords/lane/tile). VALUBusy fell to 52% (scratch stalls).
// R10 (this): de-spill R9. Live-state audit: aW2+aG 64 + acc 32 + frags 8 +
//     b2C 16 + temps ~20 = ~140 regs -> fits (3,3) cap 168, NOT (4,4) cap 128.
//   - waves_per_eu(3,3), grid 1536 (R7 proved 3 waves suffice when VALU-bound)
//   - w30/w31 LDS reads back inside epilogue (not live across MFMA section)
//   - keep pk_fma/pk_mul/pk_add, b2-in-C, bare v_exp_f32
//   - elu(a) = max(a, e-1), e = exp(min(a,0)) (exact by convexity; saves one
//     pk_add per element pair)
// Layouts (m120-verified): A[m=col][k=jt*32+quad*8+jj], B[k][n=col],
//   D[m=mt*16+quad*4+i][n=col].

typedef short bf16x8 __attribute__((ext_vector_type(8)));
typedef float f32x4  __attribute__((ext_vector_type(4)));
typedef float f32x2  __attribute__((ext_vector_type(2)));
typedef int   i32x4  __attribute__((ext_vector_type(4)));

#define LO2(v) __builtin_shufflevector(v, v, 0, 1)
#define HI2(v) __builtin_shufflevector(v, v, 2, 3)

static __device__ __forceinline__ short f2bf(float x) {
    __hip_bfloat16 b = __float2bfloat16(x);
    return __builtin_bit_cast(short, b);
}

// one dword = bf16(lo) | bf16(hi)<<16, single HW instruction
static __device__ __forceinline__ int cvt_pk_bf16(float lo, float hi) {
    int r;
    asm("v_cvt_pk_bf16_f32 %0, %1, %2" : "=v"(r) : "v"(lo), "v"(hi));
    return r;
}

__global__ __launch_bounds__(256) __attribute__((amdgpu_waves_per_eu(3, 3)))
void odefunc_mfma(const float* __restrict__ zin,
                  const float* __restrict__ W1, const float* __restrict__ b1,
                  const float* __restrict__ W2, const float* __restrict__ b2,
                  const float* __restrict__ W3, const float* __restrict__ b3,
                  float* __restrict__ out, int B, int ntiles)
{
    // LDS constant bank, f32x4 units: [0..15]=W1 col0, [16..31]=W1 col1,
    // [32..47]=b1, [48..63]=b2, [64..79]=W3 row0, [80..95]=W3 row1
    __shared__ f32x4 sC[96];

    const int lane = threadIdx.x & 63;
    const int quad = lane >> 4;      // 0..3
    const int col  = lane & 15;      // row-within-tile

    if (threadIdx.x < 64) {
        int i = threadIdx.x;
        float* s = (float*)sC;
        s[i]       = W1[2*i];
        s[64 + i]  = W1[2*i + 1];
        s[128 + i] = b1[i];
        s[192 + i] = b2[i];
        s[256 + i] = W3[i];         // W3[0,:]
        s[320 + i] = W3[64 + i];    // W3[1,:]
    }

    const int wid    = blockIdx.x * (blockDim.x >> 6) + (threadIdx.x >> 6);
    const int nwaves = gridDim.x * (blockDim.x >> 6);

    // ---- Loop-invariant A-operand fragments: W2 and G (trace-folded W2) ----
    // G[k,j] = W2[k,j] * (W3[0,k]*W1[j,0] + W3[1,k]*W1[j,1])
    bf16x8 aW2[4][2], aG[4][2];
#pragma unroll
    for (int mt = 0; mt < 4; ++mt) {
        const int k = mt * 16 + col;
        const float ck = W3[k], dk = W3[64 + k];
#pragma unroll
        for (int jt = 0; jt < 2; ++jt) {
            const float* p = W2 + k * 64 + jt * 32 + quad * 8;
#pragma unroll
            for (int jj = 0; jj < 8; ++jj) {
                int j = jt * 32 + quad * 8 + jj;
                float w2 = p[jj];
                aW2[mt][jt][jj] = f2bf(w2);
                aG[mt][jt][jj]  = f2bf(w2 * fmaf(ck, W1[2*j], dk * W1[2*j+1]));
            }
        }
    }

    const float b30 = b3[0], b31 = b3[1];
    const f32x4 zero4 = {0.f, 0.f, 0.f, 0.f};
    const f32x2 zerop = {0.f, 0.f};
    const f32x2 m1p   = {-1.f, -1.f};
    const f32x2 l2e   = {1.442695040888963f, 1.442695040888963f};

    __syncthreads();

    // ---- coalesced z: lanes 0-47 cover the tile's 16 rows x 3 floats ----
    const int lload = lane < 48 ? lane : 47;
    int t = wid;
    float zv = 0.f;
    if (t < ntiles) zv = zin[t * 48 + lload];

    int cofs = 0;   // opaque zero: defeats LICM on the sC re-reads
    for (; t < ntiles; t += nwaves) {
        asm volatile("" : "+v"(cofs));

        // prefetch next tile's z (hides HBM latency under this tile's compute)
        int tn = t + nwaves;
        int tc = tn < ntiles ? tn : t;
        float zvn = zin[tc * 48 + lload];

        float z0 = __shfl(zv, 3 * col);
        float z1 = __shfl(zv, 3 * col + 1);
        const f32x2 z0p = {z0, z0}, z1p = {z1, z1};

        // ---- layer 1 (branch-free elu, packed f32) -> B-fragments [h | ex1] ----
        bf16x8 Bh[2], Bex[2];
#pragma unroll
        for (int jt = 0; jt < 2; ++jt) {
            int j4 = cofs + jt * 8 + quad * 2;      // f32x4 idx of j0 = jt*32+quad*8
            f32x4 w0a = sC[j4],      w0b = sC[j4 + 1];
            f32x4 w1a = sC[j4 + 16], w1b = sC[j4 + 17];
            f32x4 bba = sC[j4 + 32], bbb = sC[j4 + 33];
            i32x4 ph, pe;
#pragma unroll
            for (int p = 0; p < 4; ++p) {
                f32x2 w0p = (p == 0) ? LO2(w0a) : (p == 1) ? HI2(w0a)
                           : (p == 2) ? LO2(w0b) : HI2(w0b);
                f32x2 w1p = (p == 0) ? LO2(w1a) : (p == 1) ? HI2(w1a)
                           : (p == 2) ? LO2(w1b) : HI2(w1b);
                f32x2 bbp = (p == 0) ? LO2(bba) : (p == 1) ? HI2(bba)
                           : (p == 2) ? LO2(bbb) : HI2(bbb);
                f32x2 a  = __builtin_elementwise_fma(w0p, z0p,
                           __builtin_elementwise_fma(w1p, z1p, bbp));   // 2x pk_fma
                f32x2 am = __builtin_elementwise_min(a, zerop);         // 2x v_min
                f32x2 tt = am * l2e;                                    // pk_mul
                f32x2 e  = { __builtin_amdgcn_exp2f(tt[0]),
                             __builtin_amdgcn_exp2f(tt[1]) };           // 2x v_exp
                f32x2 em1 = e + m1p;                                    // pk_add
                f32x2 h  = __builtin_elementwise_max(a, em1);           // 2x v_max
                ph[p] = cvt_pk_bf16(h[0], h[1]);
                pe[p] = cvt_pk_bf16(e[0], e[1]);
            }
            Bh[jt]  = __builtin_bit_cast(bf16x8, ph);
            Bex[jt] = __builtin_bit_cast(bf16x8, pe);
        }

        // ---- MFMA: accH = W2*h^T + b2 (C-init), accT = G*ex1^T ----
        f32x4 accH[4], accT[4];
#pragma unroll
        for (int mt = 0; mt < 4; ++mt) {
            f32x4 b2v = sC[cofs + 48 + mt * 4 + quad];  // k0 = mt*16+quad*4
            accH[mt] = __builtin_amdgcn_mfma_f32_16x16x32_bf16(aW2[mt][0], Bh[0], b2v, 0, 0, 0);
            accH[mt] = __builtin_amdgcn_mfma_f32_16x16x32_bf16(aW2[mt][1], Bh[1], accH[mt], 0, 0, 0);
            accT[mt] = __builtin_amdgcn_mfma_f32_16x16x32_bf16(aG[mt][0], Bex[0], zero4, 0, 0, 0);
            accT[mt] = __builtin_amdgcn_mfma_f32_16x16x32_bf16(aG[mt][1], Bex[1], accT[mt], 0, 0, 0);
        }

        // ---- epilogue (packed f32): elu + W3 fold; trace = ex2 . accT ----
        f32x2 o0p = zerop, o1p = zerop, trcp = zerop;
#pragma unroll
        for (int mt = 0; mt < 4; ++mt) {
            int k4 = cofs + 48 + mt * 4 + quad;     // f32x4 idx of k0 = mt*16+quad*4
            f32x4 w30 = sC[k4 + 16];
            f32x4 w31 = sC[k4 + 32];
#pragma unroll
            for (int half = 0; half < 2; ++half) {
                f32x2 a2  = half ? HI2(accH[mt]) : LO2(accH[mt]);   // b2 already in
                f32x2 at  = half ? HI2(accT[mt]) : LO2(accT[mt]);
                f32x2 w30p = half ? HI2(w30) : LO2(w30);
                f32x2 w31p = half ? HI2(w31) : LO2(w31);
                f32x2 am = __builtin_elementwise_min(a2, zerop);
                f32x2 tt = am * l2e;                                // pk_mul
                f32x2 e  = { __builtin_amdgcn_exp2f(tt[0]),
                             __builtin_amdgcn_exp2f(tt[1]) };
                f32x2 em1 = e + m1p;                                // pk_add
                f32x2 hh = __builtin_elementwise_max(a2, em1);      // 2x v_max
                o0p  = __builtin_elementwise_fma(w30p, hh, o0p);    // pk_fma
                o1p  = __builtin_elementwise_fma(w31p, hh, o1p);    // pk_fma
                trcp = __builtin_elementwise_fma(e, at, trcp);      // pk_fma
            }
        }
        float o0 = o0p[0] + o0p[1];
        float o1 = o1p[0] + o1p[1];
        float trc = trcp[0] + trcp[1];

        // ---- cross-quad reduction (k spans quads): 2 butterfly stages ----
        o0  += __shfl_xor(o0, 16);  o0  += __shfl_xor(o0, 32);
        o1  += __shfl_xor(o1, 16);  o1  += __shfl_xor(o1, 32);
        trc += __shfl_xor(trc, 16); trc += __shfl_xor(trc, 32);

        int row = t * 16 + col;
        if (lane < 16 && row < B) {
            out[3 * row + 0] = o0 + b30;
            out[3 * row + 1] = o1 + b31;
            out[3 * row + 2] = -trc;
        }

        zv = zvn;
    }
}

extern "C" void kernel_launch(void* const* d_in, const int* in_sizes, int n_in,
                              void* d_out, int out_size, void* d_ws, size_t ws_size,
                              hipStream_t stream) {
    // d_in: 0=t(unused) 1=z_and_logp 2=W1 3=b1 4=W2 5=b2 6=W3 7=b3
    const float* zin = (const float*)d_in[1];
    const float* W1  = (const float*)d_in[2];
    const float* b1  = (const float*)d_in[3];
    const float* W2  = (const float*)d_in[4];
    const float* b2  = (const float*)d_in[5];
    const float* W3  = (const float*)d_in[6];
    const float* b3  = (const float*)d_in[7];
    float* out = (float*)d_out;

    int B = in_sizes[1] / 3;
    int ntiles = (B + 15) / 16;
    int grid = 1536;   // 3 waves/SIMD -> 768 resident blocks -> 2 rounds
    odefunc_mfma<<<grid, 256, 0, stream>>>(zin, W1, b1, W2, b2, W3, b3,
                                           out, B, ntiles);
}

// Round 5
// 122.484 us; speedup vs baseline: 1.0693x; 1.0078x over previous
//
#include <hip/hip_runtime.h>
#include <hip/hip_bf16.h>

// ODEFunc CNF dynamics, B=1e6 rows, H=64:
//   h1 = elu(W1 z + b1); h2 = W2 h1 + b2; out01 = W3 elu(h2)+b3;
//   trace = sum_k elu'(h2_k) * (G ex1)_k with G[k,j]=W2[k,j]*(c_k w0_j + d_k w1_j)
//
// R6 74us -> R7 consts->LDS 74us (VALU-bound) -> R8 trace-fold + cvt_pk 62.5us
// -> R9 pk-f32 + waves(4,4) 64.6us REGRESSION (reg cap 128 -> spills, WRITE 4x)
// -> R10 de-spilled pk-f32 at (3,3): 58us, VALUBusy 67->53%, ~35% of cycles
//    issue nothing => now dependency-STALL-bound (long serial chain per elem:
//    lds->fma->min->mul->exp->add->max->cvt->mfma), 3 waves can't cover it,
//    4 waves spill.
// R11 (this): ILP instead of occupancy. Two independent tiles (32 rows) per
//    wave-iteration at waves_per_eu(2,2) (cap 256 regs -> no-spill headroom):
//    - two independent dep chains interleave in one instruction stream
//    - all constant LDS reads (w0/w1/b1, b2, w30/w31) + addr math shared
//      between the two tiles (per-tile overhead halves)
//    - adjacent pairing (2w, 2w+1): z loads share cache lines
// Layouts (m120-verified): A[m=col][k=jt*32+quad*8+jj], B[k][n=col],
//   D[m=mt*16+quad*4+i][n=col].

typedef short bf16x8 __attribute__((ext_vector_type(8)));
typedef float f32x4  __attribute__((ext_vector_type(4)));
typedef float f32x2  __attribute__((ext_vector_type(2)));
typedef int   i32x4  __attribute__((ext_vector_type(4)));

#define LO2(v) __builtin_shufflevector(v, v, 0, 1)
#define HI2(v) __builtin_shufflevector(v, v, 2, 3)

static __device__ __forceinline__ short f2bf(float x) {
    __hip_bfloat16 b = __float2bfloat16(x);
    return __builtin_bit_cast(short, b);
}

// one dword = bf16(lo) | bf16(hi)<<16, single HW instruction
static __device__ __forceinline__ int cvt_pk_bf16(float lo, float hi) {
    int r;
    asm("v_cvt_pk_bf16_f32 %0, %1, %2" : "=v"(r) : "v"(lo), "v"(hi));
    return r;
}

__global__ __launch_bounds__(256) __attribute__((amdgpu_waves_per_eu(2, 2)))
void odefunc_mfma(const float* __restrict__ zin,
                  const float* __restrict__ W1, const float* __restrict__ b1,
                  const float* __restrict__ W2, const float* __restrict__ b2,
                  const float* __restrict__ W3, const float* __restrict__ b3,
                  float* __restrict__ out, int B, int ntiles)
{
    // LDS constant bank, f32x4 units: [0..15]=W1 col0, [16..31]=W1 col1,
    // [32..47]=b1, [48..63]=b2, [64..79]=W3 row0, [80..95]=W3 row1
    __shared__ f32x4 sC[96];

    const int lane = threadIdx.x & 63;
    const int quad = lane >> 4;      // 0..3
    const int col  = lane & 15;      // row-within-tile

    if (threadIdx.x < 64) {
        int i = threadIdx.x;
        float* s = (float*)sC;
        s[i]       = W1[2*i];
        s[64 + i]  = W1[2*i + 1];
        s[128 + i] = b1[i];
        s[192 + i] = b2[i];
        s[256 + i] = W3[i];         // W3[0,:]
        s[320 + i] = W3[64 + i];    // W3[1,:]
    }

    const int wid    = blockIdx.x * (blockDim.x >> 6) + (threadIdx.x >> 6);
    const int nwaves = gridDim.x * (blockDim.x >> 6);

    // ---- Loop-invariant A-operand fragments: W2 and G (trace-folded W2) ----
    // G[k,j] = W2[k,j] * (W3[0,k]*W1[j,0] + W3[1,k]*W1[j,1])
    bf16x8 aW2[4][2], aG[4][2];
#pragma unroll
    for (int mt = 0; mt < 4; ++mt) {
        const int k = mt * 16 + col;
        const float ck = W3[k], dk = W3[64 + k];
#pragma unroll
        for (int jt = 0; jt < 2; ++jt) {
            const float* p = W2 + k * 64 + jt * 32 + quad * 8;
#pragma unroll
            for (int jj = 0; jj < 8; ++jj) {
                int j = jt * 32 + quad * 8 + jj;
                float w2 = p[jj];
                aW2[mt][jt][jj] = f2bf(w2);
                aG[mt][jt][jj]  = f2bf(w2 * fmaf(ck, W1[2*j], dk * W1[2*j+1]));
            }
        }
    }

    const float b30 = b3[0], b31 = b3[1];
    const f32x4 zero4 = {0.f, 0.f, 0.f, 0.f};
    const f32x2 zerop = {0.f, 0.f};
    const f32x2 m1p   = {-1.f, -1.f};
    const f32x2 l2e   = {1.442695040888963f, 1.442695040888963f};

    __syncthreads();

    // ---- coalesced z: lanes 0-47 cover a tile's 16 rows x 3 floats ----
    const int lload = lane < 48 ? lane : 47;
    int tp = wid;                     // tile-pair index: tiles 2tp, 2tp+1
    float zvA = 0.f, zvB = 0.f;
    if (2 * tp < ntiles)     zvA = zin[(2 * tp) * 48 + lload];
    if (2 * tp + 1 < ntiles) zvB = zin[(2 * tp + 1) * 48 + lload];

    int cofs = 0;   // opaque zero: defeats LICM on the sC re-reads
    for (; 2 * tp < ntiles; tp += nwaves) {
        asm volatile("" : "+v"(cofs));

        const int tA = 2 * tp, tB = 2 * tp + 1;
        const bool vB = tB < ntiles;

        // prefetch next pair's z (hides HBM latency under this pair's compute)
        int tpn = tp + nwaves;
        int tAn = 2 * tpn     < ntiles ? 2 * tpn     : 0;
        int tBn = 2 * tpn + 1 < ntiles ? 2 * tpn + 1 : 0;
        float zvAn = zin[tAn * 48 + lload];
        float zvBn = zin[tBn * 48 + lload];

        float z0A = __shfl(zvA, 3 * col), z1A = __shfl(zvA, 3 * col + 1);
        float z0B = __shfl(zvB, 3 * col), z1B = __shfl(zvB, 3 * col + 1);
        const f32x2 z0Ap = {z0A, z0A}, z1Ap = {z1A, z1A};
        const f32x2 z0Bp = {z0B, z0B}, z1Bp = {z1B, z1B};

        // ---- layer 1 (branch-free elu) for BOTH tiles, shared LDS reads ----
        bf16x8 BhA[2], BexA[2], BhB[2], BexB[2];
#pragma unroll
        for (int jt = 0; jt < 2; ++jt) {
            int j4 = cofs + jt * 8 + quad * 2;      // f32x4 idx of j0 = jt*32+quad*8
            f32x4 w0a = sC[j4],      w0b = sC[j4 + 1];
            f32x4 w1a = sC[j4 + 16], w1b = sC[j4 + 17];
            f32x4 bba = sC[j4 + 32], bbb = sC[j4 + 33];
            i32x4 phA, peA, phB, peB;
#pragma unroll
            for (int p = 0; p < 4; ++p) {
                f32x2 w0p = (p == 0) ? LO2(w0a) : (p == 1) ? HI2(w0a)
                           : (p == 2) ? LO2(w0b) : HI2(w0b);
                f32x2 w1p = (p == 0) ? LO2(w1a) : (p == 1) ? HI2(w1a)
                           : (p == 2) ? LO2(w1b) : HI2(w1b);
                f32x2 bbp = (p == 0) ? LO2(bba) : (p == 1) ? HI2(bba)
                           : (p == 2) ? LO2(bbb) : HI2(bbb);
                // tile A
                f32x2 aA  = __builtin_elementwise_fma(w0p, z0Ap,
                            __builtin_elementwise_fma(w1p, z1Ap, bbp));
                f32x2 tAm = __builtin_elementwise_min(aA, zerop) * l2e;
                f32x2 eA  = { __builtin_amdgcn_exp2f(tAm[0]),
                              __builtin_amdgcn_exp2f(tAm[1]) };
                f32x2 hA  = __builtin_elementwise_max(aA, eA + m1p);
                // tile B (independent chain -> fills A's stall slots)
                f32x2 aB  = __builtin_elementwise_fma(w0p, z0Bp,
                            __builtin_elementwise_fma(w1p, z1Bp, bbp));
                f32x2 tBm = __builtin_elementwise_min(aB, zerop) * l2e;
                f32x2 eB  = { __builtin_amdgcn_exp2f(tBm[0]),
                              __builtin_amdgcn_exp2f(tBm[1]) };
                f32x2 hB  = __builtin_elementwise_max(aB, eB + m1p);

                phA[p] = cvt_pk_bf16(hA[0], hA[1]);
                peA[p] = cvt_pk_bf16(eA[0], eA[1]);
                phB[p] = cvt_pk_bf16(hB[0], hB[1]);
                peB[p] = cvt_pk_bf16(eB[0], eB[1]);
            }
            BhA[jt]  = __builtin_bit_cast(bf16x8, phA);
            BexA[jt] = __builtin_bit_cast(bf16x8, peA);
            BhB[jt]  = __builtin_bit_cast(bf16x8, phB);
            BexB[jt] = __builtin_bit_cast(bf16x8, peB);
        }

        // ---- MFMA: accH = W2*h^T + b2 (C-init), accT = G*ex1^T, both tiles ----
        f32x4 aHA[4], aTA[4], aHB[4], aTB[4];
#pragma unroll
        for (int mt = 0; mt < 4; ++mt) {
            f32x4 b2v = sC[cofs + 48 + mt * 4 + quad];  // shared by A and B
            aHA[mt] = __builtin_amdgcn_mfma_f32_16x16x32_bf16(aW2[mt][0], BhA[0], b2v, 0, 0, 0);
            aHA[mt] = __builtin_amdgcn_mfma_f32_16x16x32_bf16(aW2[mt][1], BhA[1], aHA[mt], 0, 0, 0);
            aHB[mt] = __builtin_amdgcn_mfma_f32_16x16x32_bf16(aW2[mt][0], BhB[0], b2v, 0, 0, 0);
            aHB[mt] = __builtin_amdgcn_mfma_f32_16x16x32_bf16(aW2[mt][1], BhB[1], aHB[mt], 0, 0, 0);
            aTA[mt] = __builtin_amdgcn_mfma_f32_16x16x32_bf16(aG[mt][0], BexA[0], zero4, 0, 0, 0);
            aTA[mt] = __builtin_amdgcn_mfma_f32_16x16x32_bf16(aG[mt][1], BexA[1], aTA[mt], 0, 0, 0);
            aTB[mt] = __builtin_amdgcn_mfma_f32_16x16x32_bf16(aG[mt][0], BexB[0], zero4, 0, 0, 0);
            aTB[mt] = __builtin_amdgcn_mfma_f32_16x16x32_bf16(aG[mt][1], BexB[1], aTB[mt], 0, 0, 0);
        }

        // ---- epilogue: elu + W3 fold, both tiles, shared w30/w31 reads ----
        f32x2 o0A = zerop, o1A = zerop, trA = zerop;
        f32x2 o0B = zerop, o1B = zerop, trB = zerop;
#pragma unroll
        for (int mt = 0; mt < 4; ++mt) {
            int k4 = cofs + 48 + mt * 4 + quad;     // f32x4 idx of k0 = mt*16+quad*4
            f32x4 w30 = sC[k4 + 16];
            f32x4 w31 = sC[k4 + 32];
#pragma unroll
            for (int half = 0; half < 2; ++half) {
                f32x2 w30p = half ? HI2(w30) : LO2(w30);
                f32x2 w31p = half ? HI2(w31) : LO2(w31);
                // tile A
                f32x2 a2A = half ? HI2(aHA[mt]) : LO2(aHA[mt]);   // b2 already in
                f32x2 atA = half ? HI2(aTA[mt]) : LO2(aTA[mt]);
                f32x2 tmA = __builtin_elementwise_min(a2A, zerop) * l2e;
                f32x2 e2A = { __builtin_amdgcn_exp2f(tmA[0]),
                              __builtin_amdgcn_exp2f(tmA[1]) };
                f32x2 hhA = __builtin_elementwise_max(a2A, e2A + m1p);
                o0A = __builtin_elementwise_fma(w30p, hhA, o0A);
                o1A = __builtin_elementwise_fma(w31p, hhA, o1A);
                trA = __builtin_elementwise_fma(e2A, atA, trA);
                // tile B
                f32x2 a2B = half ? HI2(aHB[mt]) : LO2(aHB[mt]);
                f32x2 atB = half ? HI2(aTB[mt]) : LO2(aTB[mt]);
                f32x2 tmB = __builtin_elementwise_min(a2B, zerop) * l2e;
                f32x2 e2B = { __builtin_amdgcn_exp2f(tmB[0]),
                              __builtin_amdgcn_exp2f(tmB[1]) };
                f32x2 hhB = __builtin_elementwise_max(a2B, e2B + m1p);
                o0B = __builtin_elementwise_fma(w30p, hhB, o0B);
                o1B = __builtin_elementwise_fma(w31p, hhB, o1B);
                trB = __builtin_elementwise_fma(e2B, atB, trB);
            }
        }
        float o0a = o0A[0] + o0A[1], o1a = o1A[0] + o1A[1], tra = trA[0] + trA[1];
        float o0b = o0B[0] + o0B[1], o1b = o1B[0] + o1B[1], trb = trB[0] + trB[1];

        // ---- cross-quad reduction (k spans quads): 2 butterfly stages ----
        o0a += __shfl_xor(o0a, 16); o0a += __shfl_xor(o0a, 32);
        o1a += __shfl_xor(o1a, 16); o1a += __shfl_xor(o1a, 32);
        tra += __shfl_xor(tra, 16); tra += __shfl_xor(tra, 32);
        o0b += __shfl_xor(o0b, 16); o0b += __shfl_xor(o0b, 32);
        o1b += __shfl_xor(o1b, 16); o1b += __shfl_xor(o1b, 32);
        trb += __shfl_xor(trb, 16); trb += __shfl_xor(trb, 32);

        int rowA = tA * 16 + col;
        if (lane < 16 && rowA < B) {
            out[3 * rowA + 0] = o0a + b30;
            out[3 * rowA + 1] = o1a + b31;
            out[3 * rowA + 2] = -tra;
        }
        int rowB = tB * 16 + col;
        if (lane < 16 && vB && rowB < B) {
            out[3 * rowB + 0] = o0b + b30;
            out[3 * rowB + 1] = o1b + b31;
            out[3 * rowB + 2] = -trb;
        }

        zvA = zvAn;
        zvB = zvBn;
    }
}

extern "C" void kernel_launch(void* const* d_in, const int* in_sizes, int n_in,
                              void* d_out, int out_size, void* d_ws, size_t ws_size,
                              hipStream_t stream) {
    // d_in: 0=t(unused) 1=z_and_logp 2=W1 3=b1 4=W2 5=b2 6=W3 7=b3
    const float* zin = (const float*)d_in[1];
    const float* W1  = (const float*)d_in[2];
    const float* b1  = (const float*)d_in[3];
    const float* W2  = (const float*)d_in[4];
    const float* b2  = (const float*)d_in[5];
    const float* W3  = (const float*)d_in[6];
    const float* b3  = (const float*)d_in[7];
    float* out = (float*)d_out;

    int B = in_sizes[1] / 3;
    int ntiles = (B + 15) / 16;
    int grid = 1024;   // 2 waves/SIMD -> 512 resident blocks -> 2 rounds
    odefunc_mfma<<<grid, 256, 0, stream>>>(zin, W1, b1, W2, b2, W3, b3,
                                           out, B, ntiles);
}

// Round 6
// 119.854 us; speedup vs baseline: 1.0927x; 1.0219x over previous
//
#include <hip/hip_runtime.h>
#include <hip/hip_fp16.h>

// ODEFunc CNF dynamics, B=1e6 rows, H=64:
//   h1 = elu(W1 z + b1); h2 = W2 h1 + b2; out01 = W3 elu(h2)+b3;
//   trace = sum_k elu'(h2_k) * (G ex1)_k with G[k,j]=W2[k,j]*(c_k w0_j + d_k w1_j)
//
// R6 74us -> R7 consts->LDS 74us -> R8 trace-fold + cvt_pk 62.5us -> R9 pk-f32
// at (4,4) 64.6us SPILL regression -> R10 de-spilled (3,3) 58us -> R11 2-tile
// ILP at (2,2) 55.3us. R10/R11 post-mortem: VALU-busy ~1150 cyc/tile in both;
// pk_f32 is HALF-rate per component on gfx950 (FP32 peak 157.3 TF = scalar
// rate, no packed doubling) -> packing f32 saved issue slots, not cycles.
// R12 (this): layer-1 entirely in packed f16 (v_pk_*_f16 IS full-rate
// 2 elem/2cyc) + mfma_f32_16x16x32_f16 (same fragment layout as bf16):
//   - h/e computed as f16x8 ARE the MFMA fragments: all cvt_pk_bf16 and
//     repacking deleted (~36 -> ~20 cyc per element-pair)
//   - f16 has MORE mantissa than bf16 -> MFMA operands more accurate
//   - W1/b1 stored in LDS as _Float16 (ds_read_b128 = f16x8 direct)
//   - epilogue stays f32 (fold must accumulate f32); bounds checks trimmed
//     (B = 16*ntiles exactly; pair count exact for even ntiles)
// Layouts (m120-verified): A[m=col][k=jt*32+quad*8+jj], B[k][n=col],
//   D[m=mt*16+quad*4+i][n=col].

typedef _Float16 f16x8 __attribute__((ext_vector_type(8)));
typedef _Float16 f16x2 __attribute__((ext_vector_type(2)));
typedef float    f32x4 __attribute__((ext_vector_type(4)));
typedef float    f32x2 __attribute__((ext_vector_type(2)));

#define LO2(v) __builtin_shufflevector(v, v, 0, 1)
#define HI2(v) __builtin_shufflevector(v, v, 2, 3)

// packed 2x f16 exp2 -> 2x v_exp_f16
static __device__ __forceinline__ f16x8 exp2_h8(f16x8 t) {
    f16x8 e;
#pragma unroll
    for (int p = 0; p < 4; ++p) {
        f16x2 t2 = {t[2*p], t[2*p+1]};
        __half2 r = h2exp2(__builtin_bit_cast(__half2, t2));
        f16x2 e2 = __builtin_bit_cast(f16x2, r);
        e[2*p] = e2[0]; e[2*p+1] = e2[1];
    }
    return e;
}

__global__ __launch_bounds__(256) __attribute__((amdgpu_waves_per_eu(2, 2)))
void odefunc_mfma(const float* __restrict__ zin,
                  const float* __restrict__ W1, const float* __restrict__ b1,
                  const float* __restrict__ W2, const float* __restrict__ b2,
                  const float* __restrict__ W3, const float* __restrict__ b3,
                  float* __restrict__ out, int B, int ntiles)
{
    // LDS: layer-1 consts as f16 (f16x8-readable); epilogue consts as f32x4
    __shared__ _Float16 sH[192];   // [0..63]=W1 col0, [64..127]=W1 col1, [128..191]=b1
    __shared__ f32x4    sC[48];    // [0..15]=b2, [16..31]=W3 row0, [32..47]=W3 row1

    const int lane = threadIdx.x & 63;
    const int quad = lane >> 4;      // 0..3
    const int col  = lane & 15;      // row-within-tile

    if (threadIdx.x < 64) {
        int i = threadIdx.x;
        sH[i]       = (_Float16)W1[2*i];
        sH[64 + i]  = (_Float16)W1[2*i + 1];
        sH[128 + i] = (_Float16)b1[i];
        float* s = (float*)sC;
        s[i]       = b2[i];
        s[64 + i]  = W3[i];         // W3[0,:]
        s[128 + i] = W3[64 + i];    // W3[1,:]
    }

    const int wid    = blockIdx.x * (blockDim.x >> 6) + (threadIdx.x >> 6);
    const int nwaves = gridDim.x * (blockDim.x >> 6);

    // ---- Loop-invariant A-operand fragments (f16): W2 and G (trace-folded) ----
    // G[k,j] = W2[k,j] * (W3[0,k]*W1[j,0] + W3[1,k]*W1[j,1])
    f16x8 aW2[4][2], aG[4][2];
#pragma unroll
    for (int mt = 0; mt < 4; ++mt) {
        const int k = mt * 16 + col;
        const float ck = W3[k], dk = W3[64 + k];
#pragma unroll
        for (int jt = 0; jt < 2; ++jt) {
            const float* p = W2 + k * 64 + jt * 32 + quad * 8;
#pragma unroll
            for (int jj = 0; jj < 8; ++jj) {
                int j = jt * 32 + quad * 8 + jj;
                float w2 = p[jj];
                aW2[mt][jt][jj] = (_Float16)w2;
                aG[mt][jt][jj]  = (_Float16)(w2 * fmaf(ck, W1[2*j], dk * W1[2*j+1]));
            }
        }
    }

    const float b30 = b3[0], b31 = b3[1];
    const f32x4 zero4 = {0.f, 0.f, 0.f, 0.f};
    const f32x2 zerop = {0.f, 0.f};
    const f32x2 m1p   = {-1.f, -1.f};
    const f32x2 l2e   = {1.442695040888963f, 1.442695040888963f};
    const _Float16 hl2e = (_Float16)1.442695040888963f;
    const _Float16 hm1  = (_Float16)-1.0f;
    const _Float16 h0   = (_Float16)0.0f;
    const f16x8 zero8 = {h0,h0,h0,h0,h0,h0,h0,h0};
    const f16x8 l2e8  = {hl2e,hl2e,hl2e,hl2e,hl2e,hl2e,hl2e,hl2e};
    const f16x8 m18   = {hm1,hm1,hm1,hm1,hm1,hm1,hm1,hm1};

    __syncthreads();

    // ---- coalesced z: lanes 0-47 cover a tile's 16 rows x 3 floats ----
    const int lload = lane < 48 ? lane : 47;
    int tp = wid;                     // tile-pair index: tiles 2tp, 2tp+1
    float zvA = 0.f, zvB = 0.f;
    if (2 * tp < ntiles) {
        zvA = zin[(2 * tp) * 48 + lload];
        if (2 * tp + 1 < ntiles) zvB = zin[(2 * tp + 1) * 48 + lload];
    }

    int cofs = 0;   // opaque zero: defeats LICM on the LDS re-reads
    for (; 2 * tp < ntiles; tp += nwaves) {
        asm volatile("" : "+v"(cofs));

        const int tA = 2 * tp, tB = 2 * tp + 1;
        const bool vB = tB < ntiles;

        // prefetch next pair's z (hides HBM latency under this pair's compute)
        int tpn = tp + nwaves;
        int tAn = 2 * tpn     < ntiles ? 2 * tpn     : 0;
        int tBn = 2 * tpn + 1 < ntiles ? 2 * tpn + 1 : 0;
        float zvAn = zin[tAn * 48 + lload];
        float zvBn = zin[tBn * 48 + lload];

        float z0A = __shfl(zvA, 3 * col), z1A = __shfl(zvA, 3 * col + 1);
        float z0B = __shfl(zvB, 3 * col), z1B = __shfl(zvB, 3 * col + 1);
        const _Float16 z0Ah = (_Float16)z0A, z1Ah = (_Float16)z1A;
        const _Float16 z0Bh = (_Float16)z0B, z1Bh = (_Float16)z1B;
        const f16x8 z0A8 = {z0Ah,z0Ah,z0Ah,z0Ah,z0Ah,z0Ah,z0Ah,z0Ah};
        const f16x8 z1A8 = {z1Ah,z1Ah,z1Ah,z1Ah,z1Ah,z1Ah,z1Ah,z1Ah};
        const f16x8 z0B8 = {z0Bh,z0Bh,z0Bh,z0Bh,z0Bh,z0Bh,z0Bh,z0Bh};
        const f16x8 z1B8 = {z1Bh,z1Bh,z1Bh,z1Bh,z1Bh,z1Bh,z1Bh,z1Bh};

        // ---- layer 1 (branch-free elu, packed f16): fragments ARE the results ----
        f16x8 BhA[2], BeA[2], BhB[2], BeB[2];
#pragma unroll
        for (int jt = 0; jt < 2; ++jt) {
            int j0 = cofs + jt * 32 + quad * 8;
            f16x8 w0v = *(const f16x8*)(sH + j0);
            f16x8 w1v = *(const f16x8*)(sH + j0 + 64);
            f16x8 bbv = *(const f16x8*)(sH + j0 + 128);
            // tile A
            f16x8 aA = __builtin_elementwise_fma(w0v, z0A8,
                       __builtin_elementwise_fma(w1v, z1A8, bbv));
            f16x8 eA = exp2_h8(__builtin_elementwise_min(aA, zero8) * l2e8);
            f16x8 hA = __builtin_elementwise_max(aA, eA + m18);
            // tile B (independent chain)
            f16x8 aB = __builtin_elementwise_fma(w0v, z0B8,
                       __builtin_elementwise_fma(w1v, z1B8, bbv));
            f16x8 eB = exp2_h8(__builtin_elementwise_min(aB, zero8) * l2e8);
            f16x8 hB = __builtin_elementwise_max(aB, eB + m18);
            BhA[jt] = hA; BeA[jt] = eA;
            BhB[jt] = hB; BeB[jt] = eB;
        }

        // ---- MFMA (f16): accH = W2*h^T + b2 (C-init), accT = G*e^T ----
        f32x4 aHA[4], aTA[4], aHB[4], aTB[4];
#pragma unroll
        for (int mt = 0; mt < 4; ++mt) {
            f32x4 b2v = sC[cofs + mt * 4 + quad];   // k0 = mt*16+quad*4, shared A/B
            aHA[mt] = __builtin_amdgcn_mfma_f32_16x16x32_f16(aW2[mt][0], BhA[0], b2v, 0, 0, 0);
            aHA[mt] = __builtin_amdgcn_mfma_f32_16x16x32_f16(aW2[mt][1], BhA[1], aHA[mt], 0, 0, 0);
            aHB[mt] = __builtin_amdgcn_mfma_f32_16x16x32_f16(aW2[mt][0], BhB[0], b2v, 0, 0, 0);
            aHB[mt] = __builtin_amdgcn_mfma_f32_16x16x32_f16(aW2[mt][1], BhB[1], aHB[mt], 0, 0, 0);
            aTA[mt] = __builtin_amdgcn_mfma_f32_16x16x32_f16(aG[mt][0], BeA[0], zero4, 0, 0, 0);
            aTA[mt] = __builtin_amdgcn_mfma_f32_16x16x32_f16(aG[mt][1], BeA[1], aTA[mt], 0, 0, 0);
            aTB[mt] = __builtin_amdgcn_mfma_f32_16x16x32_f16(aG[mt][0], BeB[0], zero4, 0, 0, 0);
            aTB[mt] = __builtin_amdgcn_mfma_f32_16x16x32_f16(aG[mt][1], BeB[1], aTB[mt], 0, 0, 0);
        }

        // ---- epilogue (f32): elu + W3 fold; trace = ex2 . accT ----
        f32x2 o0A = zerop, o1A = zerop, trA = zerop;
        f32x2 o0B = zerop, o1B = zerop, trB = zerop;
#pragma unroll
        for (int mt = 0; mt < 4; ++mt) {
            int k4 = cofs + mt * 4 + quad;      // f32x4 idx of k0 = mt*16+quad*4
            f32x4 w30 = sC[k4 + 16];
            f32x4 w31 = sC[k4 + 32];
#pragma unroll
            for (int half = 0; half < 2; ++half) {
                f32x2 w30p = half ? HI2(w30) : LO2(w30);
                f32x2 w31p = half ? HI2(w31) : LO2(w31);
                // tile A
                f32x2 a2A = half ? HI2(aHA[mt]) : LO2(aHA[mt]);   // b2 already in
                f32x2 atA = half ? HI2(aTA[mt]) : LO2(aTA[mt]);
                f32x2 tmA = __builtin_elementwise_min(a2A, zerop) * l2e;
                f32x2 e2A = { __builtin_amdgcn_exp2f(tmA[0]),
                              __builtin_amdgcn_exp2f(tmA[1]) };
                f32x2 hhA = __builtin_elementwise_max(a2A, e2A + m1p);
                o0A = __builtin_elementwise_fma(w30p, hhA, o0A);
                o1A = __builtin_elementwise_fma(w31p, hhA, o1A);
                trA = __builtin_elementwise_fma(e2A, atA, trA);
                // tile B
                f32x2 a2B = half ? HI2(aHB[mt]) : LO2(aHB[mt]);
                f32x2 atB = half ? HI2(aTB[mt]) : LO2(aTB[mt]);
                f32x2 tmB = __builtin_elementwise_min(a2B, zerop) * l2e;
                f32x2 e2B = { __builtin_amdgcn_exp2f(tmB[0]),
                              __builtin_amdgcn_exp2f(tmB[1]) };
                f32x2 hhB = __builtin_elementwise_max(a2B, e2B + m1p);
                o0B = __builtin_elementwise_fma(w30p, hhB, o0B);
                o1B = __builtin_elementwise_fma(w31p, hhB, o1B);
                trB = __builtin_elementwise_fma(e2B, atB, trB);
            }
        }
        float o0a = o0A[0] + o0A[1], o1a = o1A[0] + o1A[1], tra = trA[0] + trA[1];
        float o0b = o0B[0] + o0B[1], o1b = o1B[0] + o1B[1], trb = trB[0] + trB[1];

        // ---- cross-quad reduction (k spans quads): 2 butterfly stages ----
        o0a += __shfl_xor(o0a, 16); o0a += __shfl_xor(o0a, 32);
        o1a += __shfl_xor(o1a, 16); o1a += __shfl_xor(o1a, 32);
        tra += __shfl_xor(tra, 16); tra += __shfl_xor(tra, 32);
        o0b += __shfl_xor(o0b, 16); o0b += __shfl_xor(o0b, 32);
        o1b += __shfl_xor(o1b, 16); o1b += __shfl_xor(o1b, 32);
        trb += __shfl_xor(trb, 16); trb += __shfl_xor(trb, 32);

        int rowA = tA * 16 + col;
        if (lane < 16 && rowA < B) {
            out[3 * rowA + 0] = o0a + b30;
            out[3 * rowA + 1] = o1a + b31;
            out[3 * rowA + 2] = -tra;
        }
        int rowB = tB * 16 + col;
        if (lane < 16 && vB && rowB < B) {
            out[3 * rowB + 0] = o0b + b30;
            out[3 * rowB + 1] = o1b + b31;
            out[3 * rowB + 2] = -trb;
        }

        zvA = zvAn;
        zvB = zvBn;
    }
}

extern "C" void kernel_launch(void* const* d_in, const int* in_sizes, int n_in,
                              void* d_out, int out_size, void* d_ws, size_t ws_size,
                              hipStream_t stream) {
    // d_in: 0=t(unused) 1=z_and_logp 2=W1 3=b1 4=W2 5=b2 6=W3 7=b3
    const float* zin = (const float*)d_in[1];
    const float* W1  = (const float*)d_in[2];
    const float* b1  = (const float*)d_in[3];
    const float* W2  = (const float*)d_in[4];
    const float* b2  = (const float*)d_in[5];
    const float* W3  = (const float*)d_in[6];
    const float* b3  = (const float*)d_in[7];
    float* out = (float*)d_out;

    int B = in_sizes[1] / 3;
    int ntiles = (B + 15) / 16;
    int grid = 1024;   // 2 waves/SIMD -> 512 resident blocks -> 2 rounds
    odefunc_mfma<<<grid, 256, 0, stream>>>(zin, W1, b1, W2, b2, W3, b3,
                                           out, B, ntiles);
}